// Round 6
// baseline (15902.621 us; speedup 1.0000x reference)
//
#include <hip/hip_runtime.h>
#include <hip/hip_bf16.h>
#include <hip/hip_fp16.h>

typedef unsigned short u16;
typedef unsigned int u32;
typedef short s16x8 __attribute__((ext_vector_type(8)));
typedef float f32x4 __attribute__((ext_vector_type(4)));
typedef _Float16 hf2 __attribute__((ext_vector_type(2)));

#define FE_LD 2944
#define EDGE_LD 2816

static __device__ __forceinline__ hf2 u_as_hf2(u32 u){ return __builtin_bit_cast(hf2, u); }
static __device__ __forceinline__ float fdot2(u32 a, u32 b, float acc) {
  return __builtin_amdgcn_fdot2(u_as_hf2(a), u_as_hf2(b), acc, false);
}

static __device__ __forceinline__ float fsig(float x) {
  return __builtin_amdgcn_rcpf(1.f + __expf(-x));
}
static __device__ __forceinline__ float ftanh(float x) {
  return 1.f - 2.f * __builtin_amdgcn_rcpf(1.f + __expf(2.f * x));
}

#define GLD_LDS16(gsrc, ldst) \
  __builtin_amdgcn_global_load_lds((const __attribute__((address_space(1))) void*)(gsrc), \
                                   (__attribute__((address_space(3))) void*)(ldst), 16, 0, 0)

// ---------------------------------------------------------------------------
// Generic bf16 MFMA GEMM: C[M=4096][N] = A[M][K] * B^T[N][K] (+bias), K%64==0.
// 128x128 tile, 4 waves (2x2), 4x4 frags of 16x16x32.
// Staging: global_load_lds width=16, linear LDS dest + pre-swizzled source.
// ---------------------------------------------------------------------------
__global__ __launch_bounds__(256) void gemm_kernel(
    const u16* __restrict__ A, int lda,
    const u16* __restrict__ B, int ldb,
    int K, int N,
    float* __restrict__ outF, __hip_bfloat16* __restrict__ outB, int ldc,
    const float* __restrict__ bias)
{
  __shared__ __align__(16) u16 As[128*64];
  __shared__ __align__(16) u16 Bs[128*64];
  const int tid = threadIdx.x;
  const int w = tid >> 6, lane = tid & 63;
  const int wm = w >> 1, wn = w & 1;
  const long bm = (long)blockIdx.x * 128;
  const long bn = (long)blockIdx.y * 128;
  f32x4 acc[4][4] = {};

  for (int k0 = 0; k0 < K; k0 += 64) {
    #pragma unroll
    for (int rr = 0; rr < 4; rr++) {
      int idx = rr * 256 + tid;
      int row = idx >> 3;
      int g   = idx & 7;
      int gs  = g ^ (row & 7);                 // pre-swizzled source group
      int ldst = (rr * 256 + (w << 6)) * 8;    // linear wave-uniform dest (elems)
      GLD_LDS16(A + (bm + row) * (long)lda + k0 + gs * 8, &As[ldst]);
      GLD_LDS16(B + (bn + row) * (long)ldb + k0 + gs * 8, &Bs[ldst]);
    }
    __syncthreads();
    #pragma unroll
    for (int kk = 0; kk < 2; kk++) {
      s16x8 af[4], bfr[4];
      #pragma unroll
      for (int i = 0; i < 4; i++) {
        int ra = wm * 64 + i * 16 + (lane & 15);
        int rb = wn * 64 + i * 16 + (lane & 15);
        int gg = kk * 4 + (lane >> 4);
        af[i]  = *(const s16x8*)&As[ra * 64 + ((gg ^ (ra & 7)) << 3)];
        bfr[i] = *(const s16x8*)&Bs[rb * 64 + ((gg ^ (rb & 7)) << 3)];
      }
      #pragma unroll
      for (int i = 0; i < 4; i++)
        #pragma unroll
        for (int j = 0; j < 4; j++)
          acc[i][j] = __builtin_amdgcn_mfma_f32_16x16x32_bf16(af[i], bfr[j], acc[i][j], 0, 0, 0);
    }
    __syncthreads();
  }

  #pragma unroll
  for (int i = 0; i < 4; i++)
    #pragma unroll
    for (int j = 0; j < 4; j++)
      #pragma unroll
      for (int v = 0; v < 4; v++) {
        long rr = bm + wm * 64 + i * 16 + (lane >> 4) * 4 + v;
        int  cc = (int)bn + wn * 64 + j * 16 + (lane & 15);
        if (cc < N) {
          float val = acc[i][j][v] + (bias ? bias[cc] : 0.f);
          if (outF) outF[rr * (long)ldc + cc] = val;
          else      outB[rr * (long)ldc + cc] = __float2bfloat16(val);
        }
      }
}

// ---------------------------------------------------------------------------
// Tiled transpose + cast fp32 -> bf16, zero pad, optional row remap.
// dst[n][k] = src[srck][n]
// ---------------------------------------------------------------------------
__global__ void transpose_cast(const float* __restrict__ src, __hip_bfloat16* __restrict__ dst,
                               int srcK, int srcN, int dstR, int dstC, int split, int split_off)
{
  __shared__ float tile[32][33];
  const int kt = blockIdx.x * 32, nt = blockIdx.y * 32;
  const int tx = threadIdx.x & 31, ty = threadIdx.x >> 5;
  for (int i = ty; i < 32; i += 8) {
    int k = kt + i;
    int srck = (k < split) ? (split_off + k) : (k - split);
    int n = nt + tx;
    tile[i][tx] = (srck < srcK && n < srcN) ? src[(size_t)srck * srcN + n] : 0.f;
  }
  __syncthreads();
  for (int i = ty; i < 32; i += 8) {
    int n = nt + i, k = kt + tx;
    if (n < dstR && k < dstC)
      dst[(size_t)n * dstC + k] = __float2bfloat16(tile[tx][i]);
  }
}

// ---------------------------------------------------------------------------
// Pack whh fp32 [2][256][1024] -> f16-pair u32 for the h-quad rec kernel.
// wq[(((d*4+q)*4+kg)*32+p)*256 + c] = pack(whh[d][kg*64+2p][gc], whh[d][kg*64+2p+1][gc])
//   where c: gate g=c>>6, j=c&63; gc = g*256 + q*64 + j.
// idx bits: d<<17 | q<<15 | kg<<13 | p<<8 | c   (262144 per weight set)
// ---------------------------------------------------------------------------
__global__ void pack_whh(const float* __restrict__ whh, u32* __restrict__ wq)
{
  const int idx = blockIdx.x * 1024 + threadIdx.x;
  const int c  = idx & 255;
  const int p  = (idx >> 8) & 31;
  const int kg = (idx >> 13) & 3;
  const int q  = (idx >> 15) & 3;
  const int d  = (idx >> 17) & 1;
  const int gc = (c >> 6) * 256 + q * 64 + (c & 63);
  const int k0 = kg * 64 + 2 * p;
  const float* s = whh + ((size_t)d * 256 + k0) * 1024 + gc;
  __half2 h = __floats2half2_rn(s[0], s[1024]);
  wq[idx] = __builtin_bit_cast(u32, h);
}

// ---------------------------------------------------------------------------
// prep: softmax(151), probs->bf16 (padded 192), conf=max(probs[1:]),
// pos = relu(BN(center_size(boxes)) @ pos_w + pos_b), fmaps -> FE bf16.
// FE layout: [enc 0..512 | fmaps 512..2560 | embed 2560..2760 | pos 2760..2888 | pad]
// ---------------------------------------------------------------------------
__global__ void prep_kernel(
    const float* __restrict__ logits, const float* __restrict__ fmaps,
    const float* __restrict__ boxes,
    const float* __restrict__ bn_g, const float* __restrict__ bn_b,
    const float* __restrict__ bn_m, const float* __restrict__ bn_v,
    const float* __restrict__ pos_w, const float* __restrict__ pos_b,
    __hip_bfloat16* __restrict__ FE, __hip_bfloat16* __restrict__ probsb,
    float* __restrict__ conf)
{
  __shared__ float red[256];
  const int row = blockIdx.x, t = threadIdx.x;
  float v = (t < 151) ? logits[(size_t)row * 151 + t] : -3.0e38f;
  red[t] = v; __syncthreads();
  for (int s = 128; s > 0; s >>= 1) { if (t < s) red[t] = fmaxf(red[t], red[t + s]); __syncthreads(); }
  float mx = red[0]; __syncthreads();
  float p = (t < 151) ? expf(v - mx) : 0.f;
  red[t] = p; __syncthreads();
  for (int s = 128; s > 0; s >>= 1) { if (t < s) red[t] += red[t + s]; __syncthreads(); }
  float sum = red[0]; __syncthreads();
  p = p / sum;
  if (t < 192) probsb[(size_t)row * 192 + t] = __float2bfloat16((t < 151) ? p : 0.f);
  red[t] = (t >= 1 && t < 151) ? p : 0.f; __syncthreads();
  for (int s = 128; s > 0; s >>= 1) { if (t < s) red[t] = fmaxf(red[t], red[t + s]); __syncthreads(); }
  if (t == 0) conf[row] = red[0];

  if (t < 128) {
    float x1 = boxes[row * 4 + 0], y1 = boxes[row * 4 + 1];
    float x2 = boxes[row * 4 + 2], y2 = boxes[row * 4 + 3];
    float cs[4] = { (x1 + x2) * 0.5f, (y1 + y2) * 0.5f, x2 - x1, y2 - y1 };
    float a = pos_b[t];
    #pragma unroll
    for (int j = 0; j < 4; j++) {
      float cn = (cs[j] - bn_m[j]) * rsqrtf(bn_v[j] + 1e-5f) * bn_g[j] + bn_b[j];
      a += cn * pos_w[j * 128 + t];
    }
    FE[(size_t)row * FE_LD + 2760 + t] = __float2bfloat16(fmaxf(a, 0.f));
  }
  for (int c0 = t; c0 < 2048; c0 += 256)
    FE[(size_t)row * FE_LD + 512 + c0] = __float2bfloat16(fmaps[(size_t)row * 2048 + c0]);
}

// ---------------------------------------------------------------------------
// Per-image bitonic sort of conf desc (tie: index asc) -> perm (global rows).
// ---------------------------------------------------------------------------
__global__ void sort_kernel(const float* __restrict__ conf, int* __restrict__ perm)
{
  __shared__ float key[128];
  __shared__ int   idx[128];
  const int b = blockIdx.x, t = threadIdx.x;
  key[t] = conf[b * 128 + t]; idx[t] = t;
  __syncthreads();
  for (int k = 2; k <= 128; k <<= 1)
    for (int j = k >> 1; j > 0; j >>= 1) {
      int ixj = t ^ j;
      if (ixj > t) {
        bool up = (t & k) == 0;
        float ka = key[t], kb = key[ixj];
        int ia = idx[t], ib = idx[ixj];
        bool before = (ka > kb) || (ka == kb && ia < ib); // desc, stable
        if (before != up) { key[t] = kb; key[ixj] = ka; idx[t] = ib; idx[ixj] = ia; }
      }
      __syncthreads();
    }
  perm[b * 128 + t] = b * 128 + idx[t];
}

// ---------------------------------------------------------------------------
// LSTM scan, h-quad split. 256 blocks = (img 32, dir 2, quarter 4), 1024 thr
// = 4 k-groups x 256 gate-cols. Block owns h-dims [q*64, q*64+64); thread
// (kg, c) computes W·h partial for gate col c over k in [kg*64, kg*64+64)
// with 32 weight u32 in registers (fits the 64-VGPR budget -> no spill).
// k-group kg needs only quarter kg's h: own quarter from LDS, others via
// global hx[t] + agent-scope release/acquire flags (cross-XCD safe).
// 256 blocks <= 256 CUs -> all co-resident -> spin-wait is deadlock-free.
// ---------------------------------------------------------------------------
__global__ __launch_bounds__(1024) void rec_kernel(
    const float* __restrict__ P,          // [4096][2048] pre-activations (+bias)
    const int* __restrict__ perm,         // [4096] global rows
    const u32* __restrict__ wq,           // [2][4][4][32][256]
    u32* __restrict__ hx,                 // [64][128][128] u32 (seq, t, h-pairs)
    int* __restrict__ flags,              // [64][4]
    int gatherPerm, int outPerm,
    __hip_bfloat16* __restrict__ out_bf, int out_ld,
    float* __restrict__ out_f32, int f32_ld, int f32_off)
{
  __shared__ float part[4 * 256];
  __shared__ __align__(16) __half h_lds[64];
  __shared__ int prow_lds[128];
  const int tid = threadIdx.x;
  const int b = blockIdx.x;
  const int img = b & 31, dir = (b >> 5) & 1, q = b >> 6;
  const int kg = tid >> 8, c = tid & 255;
  const int g = c >> 6, j = c & 63;

  u32 wv[32];
  {
    const u32* wp = wq + ((size_t)((dir * 4 + q) * 4 + kg) * 32) * 256 + c;
    #pragma unroll
    for (int i = 0; i < 32; i++) wv[i] = wp[i * 256];
  }
  #pragma unroll
  for (int i = 0; i < 32; i++) asm volatile("" : "+v"(wv[i]));   // forbid remat

  if (tid < 128) prow_lds[tid] = perm[img * 128 + tid];
  float cst = 0.f;                       // cell state (tid<64 only)
  __syncthreads();

  const int sd = img * 2 + dir;
  u32* hx_my = hx + (size_t)sd * 128 * 128;
  int* flagp = flags + sd * 4;
  const int pcol = dir * 1024 + g * 256 + q * 64 + j;

  int st = dir ? 127 : 0;
  float pcur = 0.f;
  if (kg == 0) {
    int prow0 = gatherPerm ? prow_lds[st] : (img * 128 + st);
    pcur = P[(size_t)prow0 * 2048 + pcol];
  }

  for (int t = 0; t < 128; t++) {
    float pnext = 0.f;
    if (kg == 0 && t < 127) {
      int stn = dir ? (126 - t) : (t + 1);
      int prn = gatherPerm ? prow_lds[stn] : (img * 128 + stn);
      pnext = P[(size_t)prn * 2048 + pcol];
    }
    float acc = (kg == 0) ? pcur : 0.f;

    if (t > 0) {
      if (kg == q) {
        const uint4* hp = (const uint4*)h_lds;      // own quarter, from LDS
        #pragma unroll
        for (int i = 0; i < 8; i++) {
          uint4 hv = hp[i];
          acc = fdot2(hv.x, wv[i * 4 + 0], acc);
          acc = fdot2(hv.y, wv[i * 4 + 1], acc);
          acc = fdot2(hv.z, wv[i * 4 + 2], acc);
          acc = fdot2(hv.w, wv[i * 4 + 3], acc);
        }
      } else {
        while (__hip_atomic_load(flagp + kg, __ATOMIC_ACQUIRE, __HIP_MEMORY_SCOPE_AGENT) < t)
          __builtin_amdgcn_s_sleep(2);
        const uint4* hp = (const uint4*)(hx_my + (size_t)(t - 1) * 128 + kg * 32);
        #pragma unroll
        for (int i = 0; i < 8; i++) {
          uint4 hv = hp[i];
          acc = fdot2(hv.x, wv[i * 4 + 0], acc);
          acc = fdot2(hv.y, wv[i * 4 + 1], acc);
          acc = fdot2(hv.z, wv[i * 4 + 2], acc);
          acc = fdot2(hv.w, wv[i * 4 + 3], acc);
        }
      }
    }
    part[kg * 256 + c] = acc;
    __syncthreads();

    if (tid < 64) {
      float gi = part[0 * 256 + 0 * 64 + tid] + part[1 * 256 + 0 * 64 + tid]
               + part[2 * 256 + 0 * 64 + tid] + part[3 * 256 + 0 * 64 + tid];
      float gf = part[0 * 256 + 1 * 64 + tid] + part[1 * 256 + 1 * 64 + tid]
               + part[2 * 256 + 1 * 64 + tid] + part[3 * 256 + 1 * 64 + tid];
      float gg = part[0 * 256 + 2 * 64 + tid] + part[1 * 256 + 2 * 64 + tid]
               + part[2 * 256 + 2 * 64 + tid] + part[3 * 256 + 2 * 64 + tid];
      float go = part[0 * 256 + 3 * 64 + tid] + part[1 * 256 + 3 * 64 + tid]
               + part[2 * 256 + 3 * 64 + tid] + part[3 * 256 + 3 * 64 + tid];
      float si = fsig(gi), sf = fsig(gf), so = fsig(go);
      cst = sf * cst + si * ftanh(gg);
      float h = so * ftanh(cst);
      h_lds[tid] = __float2half(h);
      const int orow = outPerm ? prow_lds[st] : (img * 128 + st);
      const int ocol = dir * 256 + q * 64 + tid;
      if (out_bf)  out_bf[(size_t)orow * out_ld + ocol] = __float2bfloat16(h);
      if (out_f32) out_f32[(size_t)orow * f32_ld + f32_off + ocol] = h;
      // publish h pairs (cross-wave shuffle within wave 0)
      float h0 = __shfl(h, 2 * (tid & 31), 64);
      float h1 = __shfl(h, 2 * (tid & 31) + 1, 64);
      if (tid < 32) {
        __half2 hp2 = __floats2half2_rn(h0, h1);
        __hip_atomic_store(hx_my + (size_t)t * 128 + q * 32 + tid,
                           __builtin_bit_cast(u32, hp2),
                           __ATOMIC_RELAXED, __HIP_MEMORY_SCOPE_AGENT);
      }
    }
    if (tid == 0)
      __hip_atomic_store(flagp + q, t + 1, __ATOMIC_RELEASE, __HIP_MEMORY_SCOPE_AGENT);
    __syncthreads();
    pcur = pnext;
    st = dir ? (st - 1) : (st + 1);
  }
}

// ---------------------------------------------------------------------------
// argmax over obj_dists[:,1:151) -> preds (first max wins, like jnp.argmax)
// ---------------------------------------------------------------------------
__global__ void argmax_kernel(const float* __restrict__ dists, int* __restrict__ preds)
{
  const int row = blockIdx.x * 4 + (threadIdx.x >> 6);
  const int lane = threadIdx.x & 63;
  float best = -3.4e38f; int bi = 1000;
  for (int cc = 1 + lane; cc < 151; cc += 64) {
    float v = dists[(size_t)row * 663 + cc];
    if (v > best) { best = v; bi = cc; }
  }
  for (int off = 32; off > 0; off >>= 1) {
    float ov = __shfl_down(best, off);
    int   oi = __shfl_down(bi, off);
    if (ov > best || (ov == best && oi < bi)) { best = ov; bi = oi; }
  }
  if (lane == 0) preds[row] = bi;
}

// ---------------------------------------------------------------------------
// edge_in = [embed2[pred] (200) | enc (512, from FE) | fmaps (2048)] bf16
// ---------------------------------------------------------------------------
__global__ void edge_build(const int* __restrict__ preds,
                           const float* __restrict__ embed2,
                           const float* __restrict__ fmaps,
                           const __hip_bfloat16* __restrict__ FE,
                           __hip_bfloat16* __restrict__ EDGE)
{
  const int row = blockIdx.x, t = threadIdx.x;
  const int pr = preds[row];
  for (int c0 = t; c0 < 200; c0 += 256)
    EDGE[(size_t)row * EDGE_LD + c0] = __float2bfloat16(embed2[(size_t)pr * 200 + c0]);
  for (int c0 = t; c0 < 512; c0 += 256)
    EDGE[(size_t)row * EDGE_LD + 200 + c0] = FE[(size_t)row * FE_LD + c0];
  for (int c0 = t; c0 < 2048; c0 += 256)
    EDGE[(size_t)row * EDGE_LD + 712 + c0] = __float2bfloat16(fmaps[(size_t)row * 2048 + c0]);
}

// ---------------------------------------------------------------------------
extern "C" void kernel_launch(void* const* d_in, const int* in_sizes, int n_in,
                              void* d_out, int out_size, void* d_ws, size_t ws_size,
                              hipStream_t stream)
{
  const float* obj_fmaps    = (const float*)d_in[0];
  const float* obj_logits   = (const float*)d_in[1];
  const float* boxes        = (const float*)d_in[2];
  const float* obj_embed_w  = (const float*)d_in[4];
  const float* obj_embed2_w = (const float*)d_in[5];
  const float* bn_g = (const float*)d_in[6];
  const float* bn_b = (const float*)d_in[7];
  const float* bn_m = (const float*)d_in[8];
  const float* bn_v = (const float*)d_in[9];
  const float* pos_w = (const float*)d_in[10];
  const float* pos_b = (const float*)d_in[11];
  const float* obj_wih0 = (const float*)d_in[12];
  const float* obj_whh0 = (const float*)d_in[13];
  const float* obj_b0   = (const float*)d_in[14];
  const float* obj_wih1 = (const float*)d_in[15];
  const float* obj_whh1 = (const float*)d_in[16];
  const float* obj_b1   = (const float*)d_in[17];
  const float* edge_wih0 = (const float*)d_in[18];
  const float* edge_whh0 = (const float*)d_in[19];
  const float* edge_b0   = (const float*)d_in[20];
  const float* edge_wih1 = (const float*)d_in[21];
  const float* edge_whh1 = (const float*)d_in[22];
  const float* edge_b1   = (const float*)d_in[23];
  const float* dec_w = (const float*)d_in[24];
  const float* dec_b = (const float*)d_in[25];
  float* out = (float*)d_out;

  char* ws = (char*)d_ws;
  auto alloc = [&](size_t bytes) -> char* {
    char* p = ws; ws += (bytes + 255) & ~(size_t)255; return p;
  };
  __hip_bfloat16* FE     = (__hip_bfloat16*)alloc(4096ull * FE_LD * 2);
  __hip_bfloat16* EDGE   = (__hip_bfloat16*)alloc(4096ull * EDGE_LD * 2);
  float*          Pbuf   = (float*)alloc(4096ull * 2048 * 4);
  __hip_bfloat16* hseq   = (__hip_bfloat16*)alloc(4096ull * 512 * 2);
  __hip_bfloat16* probsb = (__hip_bfloat16*)alloc(4096ull * 192 * 2);
  __hip_bfloat16* wih0T  = (__hip_bfloat16*)alloc(2048ull * 2432 * 2);
  __hip_bfloat16* wih1T  = (__hip_bfloat16*)alloc(2048ull * 512 * 2);
  __hip_bfloat16* ewih0T = (__hip_bfloat16*)alloc(2048ull * 2816 * 2);
  __hip_bfloat16* ewih1T = (__hip_bfloat16*)alloc(2048ull * 512 * 2);
  __hip_bfloat16* embedT = (__hip_bfloat16*)alloc(256ull * 192 * 2);
  __hip_bfloat16* decT   = (__hip_bfloat16*)alloc(256ull * 2944 * 2);
  u32* whh0pk  = (u32*)alloc(262144ull * 4);
  u32* whh1pk  = (u32*)alloc(262144ull * 4);
  u32* ewhh0pk = (u32*)alloc(262144ull * 4);
  u32* ewhh1pk = (u32*)alloc(262144ull * 4);
  u32* hx      = (u32*)alloc(64ull * 128 * 128 * 4);   // 4 MB
  int* flags   = (int*)alloc(4ull * 256 * 4);          // 4 phases x 64 seq x 4 q
  int*   perm  = (int*)alloc(4096 * 4);
  float* conf  = (float*)alloc(4096 * 4);
  int*   preds = (int*)alloc(4096 * 4);
  (void)in_sizes; (void)n_in; (void)out_size; (void)ws_size;

  hipMemsetAsync(flags, 0, 4ull * 256 * 4, stream);

  auto tr = [&](const float* src, __hip_bfloat16* dst, int srcK, int srcN,
                int dstR, int dstC, int split, int soff) {
    dim3 g((dstC + 31) / 32, (dstR + 31) / 32);
    transpose_cast<<<g, dim3(256), 0, stream>>>(src, dst, srcK, srcN, dstR, dstC, split, soff);
  };
  for (int d = 0; d < 2; d++) {
    tr(obj_wih0 + (size_t)d * 2376 * 1024, wih0T + (size_t)d * 1024 * 2432, 2376, 1024, 1024, 2432, 0, 0);
    tr(obj_wih1 + (size_t)d * 512 * 1024,  wih1T + (size_t)d * 1024 * 512,  512, 1024, 1024, 512, 0, 0);
    tr(edge_wih0 + (size_t)d * 2760 * 1024, ewih0T + (size_t)d * 1024 * 2816, 2760, 1024, 1024, 2816, 0, 0);
    tr(edge_wih1 + (size_t)d * 512 * 1024,  ewih1T + (size_t)d * 1024 * 512,  512, 1024, 1024, 512, 0, 0);
  }
  tr(obj_embed_w, embedT, 151, 200, 256, 192, 0, 0);
  tr(dec_w, decT, 2888, 151, 256, 2944, 512, 2376);  // [enc|feats] ordering remap

  auto pk = [&](const float* whh, u32* dst) {
    pack_whh<<<dim3(256), dim3(1024), 0, stream>>>(whh, dst);
  };
  pk(obj_whh0, whh0pk); pk(obj_whh1, whh1pk); pk(edge_whh0, ewhh0pk); pk(edge_whh1, ewhh1pk);

  prep_kernel<<<dim3(4096), dim3(256), 0, stream>>>(
      obj_logits, obj_fmaps, boxes, bn_g, bn_b, bn_m, bn_v, pos_w, pos_b, FE, probsb, conf);
  sort_kernel<<<dim3(32), dim3(128), 0, stream>>>(conf, perm);

  auto gemm = [&](const void* A, int lda, const void* B, int ldb, int K, int N,
                  float* oF, __hip_bfloat16* oB, int ldc, const float* bias) {
    dim3 g(32, (N + 127) / 128);
    gemm_kernel<<<g, dim3(256), 0, stream>>>(
        (const u16*)A, lda, (const u16*)B, ldb, K, N, oF, oB, ldc, bias);
  };
  auto rec = [&](const float* P, const u32* wpk, int phase, int gat, int op,
                 __hip_bfloat16* ob, int old_, float* of, int fld, int foff) {
    rec_kernel<<<dim3(256), dim3(1024), 0, stream>>>(
        P, perm, wpk, hx, flags + phase * 256, gat, op, ob, old_, of, fld, foff);
  };

  // obj_embed -> FE cols [2560,2760)
  gemm(probsb, 192, embedT, 192, 192, 200, nullptr, FE + 2560, FE_LD, nullptr);
  // obj layer 0
  gemm((const u16*)FE + 512, FE_LD, wih0T, 2432, 2432, 2048, Pbuf, nullptr, 2048, obj_b0);
  rec(Pbuf, whh0pk, 0, 1, 0, hseq, 512, nullptr, 0, 0);
  // obj layer 1 -> enc into FE cols [0,512)
  gemm(hseq, 512, wih1T, 512, 512, 2048, Pbuf, nullptr, 2048, obj_b1);
  rec(Pbuf, whh1pk, 1, 0, 1, FE, FE_LD, nullptr, 0, 0);
  // decoder -> out cols [0,151)
  gemm(FE, FE_LD, decT, 2944, 2944, 151, out, nullptr, 663, dec_b);
  argmax_kernel<<<dim3(1024), dim3(256), 0, stream>>>(out, preds);
  edge_build<<<dim3(4096), dim3(256), 0, stream>>>(preds, obj_embed2_w, obj_fmaps, FE, EDGE);
  // edge layer 0
  gemm(EDGE, EDGE_LD, ewih0T, 2816, 2816, 2048, Pbuf, nullptr, 2048, edge_b0);
  rec(Pbuf, ewhh0pk, 2, 1, 0, hseq, 512, nullptr, 0, 0);
  // edge layer 1 -> out cols [151,663)
  gemm(hseq, 512, ewih1T, 512, 512, 2048, Pbuf, nullptr, 2048, edge_b1);
  rec(Pbuf, ewhh1pk, 3, 0, 1, nullptr, 0, out, 663, 151);
}

// Round 8
// 1122.552 us; speedup vs baseline: 14.1665x; 14.1665x over previous
//
#include <hip/hip_runtime.h>
#include <hip/hip_bf16.h>
#include <hip/hip_fp16.h>

typedef unsigned short u16;
typedef unsigned int u32;
typedef short s16x8 __attribute__((ext_vector_type(8)));
typedef float f32x4 __attribute__((ext_vector_type(4)));

#define FE_LD 2944
#define EDGE_LD 2816

static __device__ __forceinline__ float fsig(float x) {
  return __builtin_amdgcn_rcpf(1.f + __expf(-x));
}
static __device__ __forceinline__ float ftanh(float x) {
  return 1.f - 2.f * __builtin_amdgcn_rcpf(1.f + __expf(2.f * x));
}

#define GLD_LDS16(gsrc, ldst) \
  __builtin_amdgcn_global_load_lds((const __attribute__((address_space(1))) void*)(gsrc), \
                                   (__attribute__((address_space(3))) void*)(ldst), 16, 0, 0)

// ---------------------------------------------------------------------------
// Generic bf16 MFMA GEMM: C[M=4096][N] = A[M][K] * B^T[N][K] (+bias), K%64==0.
// 128x128 tile, 4 waves (2x2), 4x4 frags of 16x16x32.
// Staging: global_load_lds width=16, linear LDS dest + pre-swizzled source.
// ---------------------------------------------------------------------------
__global__ __launch_bounds__(256) void gemm_kernel(
    const u16* __restrict__ A, int lda,
    const u16* __restrict__ B, int ldb,
    int K, int N,
    float* __restrict__ outF, __hip_bfloat16* __restrict__ outB, int ldc,
    const float* __restrict__ bias)
{
  __shared__ __align__(16) u16 As[128*64];
  __shared__ __align__(16) u16 Bs[128*64];
  const int tid = threadIdx.x;
  const int w = tid >> 6, lane = tid & 63;
  const int wm = w >> 1, wn = w & 1;
  const long bm = (long)blockIdx.x * 128;
  const long bn = (long)blockIdx.y * 128;
  f32x4 acc[4][4] = {};

  for (int k0 = 0; k0 < K; k0 += 64) {
    #pragma unroll
    for (int rr = 0; rr < 4; rr++) {
      int idx = rr * 256 + tid;
      int row = idx >> 3;
      int g   = idx & 7;
      int gs  = g ^ (row & 7);                 // pre-swizzled source group
      int ldst = (rr * 256 + (w << 6)) * 8;    // linear wave-uniform dest (elems)
      GLD_LDS16(A + (bm + row) * (long)lda + k0 + gs * 8, &As[ldst]);
      GLD_LDS16(B + (bn + row) * (long)ldb + k0 + gs * 8, &Bs[ldst]);
    }
    __syncthreads();
    #pragma unroll
    for (int kk = 0; kk < 2; kk++) {
      s16x8 af[4], bfr[4];
      #pragma unroll
      for (int i = 0; i < 4; i++) {
        int ra = wm * 64 + i * 16 + (lane & 15);
        int rb = wn * 64 + i * 16 + (lane & 15);
        int gg = kk * 4 + (lane >> 4);
        af[i]  = *(const s16x8*)&As[ra * 64 + ((gg ^ (ra & 7)) << 3)];
        bfr[i] = *(const s16x8*)&Bs[rb * 64 + ((gg ^ (rb & 7)) << 3)];
      }
      #pragma unroll
      for (int i = 0; i < 4; i++)
        #pragma unroll
        for (int j = 0; j < 4; j++)
          acc[i][j] = __builtin_amdgcn_mfma_f32_16x16x32_bf16(af[i], bfr[j], acc[i][j], 0, 0, 0);
    }
    __syncthreads();
  }

  #pragma unroll
  for (int i = 0; i < 4; i++)
    #pragma unroll
    for (int j = 0; j < 4; j++)
      #pragma unroll
      for (int v = 0; v < 4; v++) {
        long rr = bm + wm * 64 + i * 16 + (lane >> 4) * 4 + v;
        int  cc = (int)bn + wn * 64 + j * 16 + (lane & 15);
        if (cc < N) {
          float val = acc[i][j][v] + (bias ? bias[cc] : 0.f);
          if (outF) outF[rr * (long)ldc + cc] = val;
          else      outB[rr * (long)ldc + cc] = __float2bfloat16(val);
        }
      }
}

// ---------------------------------------------------------------------------
// Tiled transpose + cast fp32 -> bf16, zero pad, optional row remap.
// dst[n][k] = src[srck][n]
// ---------------------------------------------------------------------------
__global__ void transpose_cast(const float* __restrict__ src, __hip_bfloat16* __restrict__ dst,
                               int srcK, int srcN, int dstR, int dstC, int split, int split_off)
{
  __shared__ float tile[32][33];
  const int kt = blockIdx.x * 32, nt = blockIdx.y * 32;
  const int tx = threadIdx.x & 31, ty = threadIdx.x >> 5;
  for (int i = ty; i < 32; i += 8) {
    int k = kt + i;
    int srck = (k < split) ? (split_off + k) : (k - split);
    int n = nt + tx;
    tile[i][tx] = (srck < srcK && n < srcN) ? src[(size_t)srck * srcN + n] : 0.f;
  }
  __syncthreads();
  for (int i = ty; i < 32; i += 8) {
    int n = nt + i, k = kt + tx;
    if (n < dstR && k < dstC)
      dst[(size_t)n * dstC + k] = __float2bfloat16(tile[tx][i]);
  }
}

// ---------------------------------------------------------------------------
// Quantize whh fp32 [2][256][1024] -> i8 with per-gate-column scale.
//   wreg[(d*32+i)*1024 + col]            : u32 of k {4i..4i+3}, i in [0,32)
//   wlds[((d*8+q)*1024+col)*4 + s]       : u32 of k {128+16q+4s ..}, q<8,s<4
//   wsc [d*1024 + col]                   : maxabs/(127*127) — un-scales BOTH
//                                          the w-quant (127/max) and h-quant (127)
// 2048 threads, one per (d, col).
// ---------------------------------------------------------------------------
__global__ void pack_whh(const float* __restrict__ whh, u32* __restrict__ wreg,
                         u32* __restrict__ wlds, float* __restrict__ wsc)
{
  const int idx = blockIdx.x * 256 + threadIdx.x;   // 0..2047
  const int d = idx >> 10, col = idx & 1023;
  const float* s = whh + (size_t)d * 256 * 1024 + col;
  float mx = 0.f;
  for (int k = 0; k < 256; k++) mx = fmaxf(mx, fabsf(s[(size_t)k * 1024]));
  float inv = (mx > 0.f) ? 127.f / mx : 0.f;
  wsc[d * 1024 + col] = (mx > 0.f) ? mx / (127.f * 127.f) : 0.f;
  for (int i = 0; i < 64; i++) {
    u32 v = 0;
    #pragma unroll
    for (int b = 0; b < 4; b++) {
      int q = __float2int_rn(s[(size_t)(4 * i + b) * 1024] * inv);
      q = max(-127, min(127, q));
      v |= ((u32)(q & 0xff)) << (8 * b);
    }
    if (i < 32) {
      wreg[(size_t)(d * 32 + i) * 1024 + col] = v;
    } else {
      int q8 = (i - 32) >> 2, sb = (i - 32) & 3;
      wlds[((size_t)(d * 8 + q8) * 1024 + col) * 4 + sb] = v;
    }
  }
}

// ---------------------------------------------------------------------------
// prep: softmax(151), probs->bf16 (padded 192), conf=max(probs[1:]),
// pos = relu(BN(center_size(boxes)) @ pos_w + pos_b), fmaps -> FE bf16.
// FE layout: [enc 0..512 | fmaps 512..2560 | embed 2560..2760 | pos 2760..2888 | pad]
// ---------------------------------------------------------------------------
__global__ void prep_kernel(
    const float* __restrict__ logits, const float* __restrict__ fmaps,
    const float* __restrict__ boxes,
    const float* __restrict__ bn_g, const float* __restrict__ bn_b,
    const float* __restrict__ bn_m, const float* __restrict__ bn_v,
    const float* __restrict__ pos_w, const float* __restrict__ pos_b,
    __hip_bfloat16* __restrict__ FE, __hip_bfloat16* __restrict__ probsb,
    float* __restrict__ conf)
{
  __shared__ float red[256];
  const int row = blockIdx.x, t = threadIdx.x;
  float v = (t < 151) ? logits[(size_t)row * 151 + t] : -3.0e38f;
  red[t] = v; __syncthreads();
  for (int s = 128; s > 0; s >>= 1) { if (t < s) red[t] = fmaxf(red[t], red[t + s]); __syncthreads(); }
  float mx = red[0]; __syncthreads();
  float p = (t < 151) ? expf(v - mx) : 0.f;
  red[t] = p; __syncthreads();
  for (int s = 128; s > 0; s >>= 1) { if (t < s) red[t] += red[t + s]; __syncthreads(); }
  float sum = red[0]; __syncthreads();
  p = p / sum;
  if (t < 192) probsb[(size_t)row * 192 + t] = __float2bfloat16((t < 151) ? p : 0.f);
  red[t] = (t >= 1 && t < 151) ? p : 0.f; __syncthreads();
  for (int s = 128; s > 0; s >>= 1) { if (t < s) red[t] = fmaxf(red[t], red[t + s]); __syncthreads(); }
  if (t == 0) conf[row] = red[0];

  if (t < 128) {
    float x1 = boxes[row * 4 + 0], y1 = boxes[row * 4 + 1];
    float x2 = boxes[row * 4 + 2], y2 = boxes[row * 4 + 3];
    float cs[4] = { (x1 + x2) * 0.5f, (y1 + y2) * 0.5f, x2 - x1, y2 - y1 };
    float a = pos_b[t];
    #pragma unroll
    for (int j = 0; j < 4; j++) {
      float cn = (cs[j] - bn_m[j]) * rsqrtf(bn_v[j] + 1e-5f) * bn_g[j] + bn_b[j];
      a += cn * pos_w[j * 128 + t];
    }
    FE[(size_t)row * FE_LD + 2760 + t] = __float2bfloat16(fmaxf(a, 0.f));
  }
  for (int c0 = t; c0 < 2048; c0 += 256)
    FE[(size_t)row * FE_LD + 512 + c0] = __float2bfloat16(fmaps[(size_t)row * 2048 + c0]);
}

// ---------------------------------------------------------------------------
// Per-image bitonic sort of conf desc (tie: index asc) -> perm (global rows).
// ---------------------------------------------------------------------------
__global__ void sort_kernel(const float* __restrict__ conf, int* __restrict__ perm)
{
  __shared__ float key[128];
  __shared__ int   idx[128];
  const int b = blockIdx.x, t = threadIdx.x;
  key[t] = conf[b * 128 + t]; idx[t] = t;
  __syncthreads();
  for (int k = 2; k <= 128; k <<= 1)
    for (int j = k >> 1; j > 0; j >>= 1) {
      int ixj = t ^ j;
      if (ixj > t) {
        bool up = (t & k) == 0;
        float ka = key[t], kb = key[ixj];
        int ia = idx[t], ib = idx[ixj];
        bool before = (ka > kb) || (ka == kb && ia < ib); // desc, stable
        if (before != up) { key[t] = kb; key[ixj] = ka; idx[t] = ib; idx[ixj] = ia; }
      }
      __syncthreads();
    }
  perm[b * 128 + t] = b * 128 + idx[t];
}

// ---------------------------------------------------------------------------
// LSTM scan, i8 weights. 64 blocks = (img 32) x (dir 2), 1024 threads.
// Thread c owns gate column c (full k=256): 32 weight u32 in registers
// (proven-resident size, R6) + 32 u32 in LDS (128 KB). h re-quantized to
// i8 each step by activation threads; dot via v_dot4_i32_i8 (4 MAC/inst).
// Zero per-step global weight traffic.
// ---------------------------------------------------------------------------
__global__ __launch_bounds__(1024) void rec_kernel(
    const float* __restrict__ P,          // [4096][2048] pre-activations (+bias)
    const int* __restrict__ perm,         // [4096] global rows
    const u32* __restrict__ wreg_g,       // [2][32][1024]
    const u32* __restrict__ wlds_g,       // [2][8][1024][4]
    const float* __restrict__ wsc_g,      // [2][1024]
    int gatherPerm, int outPerm,
    __hip_bfloat16* __restrict__ out_bf, int out_ld,
    float* __restrict__ out_f32, int f32_ld, int f32_off)
{
  __shared__ __align__(16) u32 wt[8 * 1024 * 4];   // 128 KB (k 128..255)
  __shared__ float garr[1024];                     // 4 KB gate pre-acts
  __shared__ __align__(16) u32 hq[64];             // 256 i8 of h
  __shared__ int prow_lds[128];
  const int tid = threadIdx.x;
  const int img = blockIdx.x & 31, dir = blockIdx.x >> 5;

  u32 wv[32];
  {
    const u32* rp = wreg_g + (size_t)dir * 32768 + tid;
    #pragma unroll
    for (int i = 0; i < 32; i++) wv[i] = rp[(size_t)i * 1024];
  }
  #pragma unroll
  for (int i = 0; i < 32; i++) asm volatile("" : "+v"(wv[i]));   // forbid remat
  {
    const uint4* lp = (const uint4*)wlds_g + (size_t)dir * 8192 + tid;
    uint4* wt4 = (uint4*)wt;
    #pragma unroll
    for (int q = 0; q < 8; q++) wt4[q * 1024 + tid] = lp[(size_t)q * 1024];
  }
  const float sc = wsc_g[dir * 1024 + tid];
  if (tid < 128) prow_lds[tid] = perm[img * 128 + tid];
  if (tid < 64) hq[tid] = 0;
  float cst = 0.f;
  __syncthreads();

  const uint4* hq4 = (const uint4*)hq;
  const uint4* wt4 = (const uint4*)wt;

  int st = dir ? 127 : 0;
  int prow0 = gatherPerm ? prow_lds[st] : (img * 128 + st);
  float pcur = P[(size_t)prow0 * 2048 + dir * 1024 + tid];

  for (int t = 0; t < 128; t++) {
    float pnext = 0.f;
    if (t < 127) {
      int stn = dir ? (126 - t) : (t + 1);
      int prn = gatherPerm ? prow_lds[stn] : (img * 128 + stn);
      pnext = P[(size_t)prn * 2048 + dir * 1024 + tid];
    }

    int acc = 0;
    #pragma unroll
    for (int q = 0; q < 8; q++) {              // k 0..127 : register weights
      uint4 hv = hq4[q];
      acc = __builtin_amdgcn_sdot4((int)hv.x, (int)wv[4 * q + 0], acc, false);
      acc = __builtin_amdgcn_sdot4((int)hv.y, (int)wv[4 * q + 1], acc, false);
      acc = __builtin_amdgcn_sdot4((int)hv.z, (int)wv[4 * q + 2], acc, false);
      acc = __builtin_amdgcn_sdot4((int)hv.w, (int)wv[4 * q + 3], acc, false);
    }
    #pragma unroll
    for (int q = 0; q < 8; q++) {              // k 128..255 : LDS weights
      uint4 hv = hq4[8 + q];
      uint4 wl = wt4[q * 1024 + tid];
      acc = __builtin_amdgcn_sdot4((int)hv.x, (int)wl.x, acc, false);
      acc = __builtin_amdgcn_sdot4((int)hv.y, (int)wl.y, acc, false);
      acc = __builtin_amdgcn_sdot4((int)hv.z, (int)wl.z, acc, false);
      acc = __builtin_amdgcn_sdot4((int)hv.w, (int)wl.w, acc, false);
    }
    garr[tid] = pcur + (float)acc * sc;
    __syncthreads();

    if (tid < 256) {
      float gi = garr[tid], gf = garr[256 + tid], gg = garr[512 + tid], go = garr[768 + tid];
      float si = fsig(gi), sf = fsig(gf), so = fsig(go);
      cst = sf * cst + si * ftanh(gg);
      float h = so * ftanh(cst);
      int qi = __float2int_rn(h * 127.f);
      ((signed char*)hq)[tid] = (signed char)qi;
      const int orow = outPerm ? prow_lds[st] : (img * 128 + st);
      if (out_bf)  out_bf[(size_t)orow * out_ld + dir * 256 + tid] = __float2bfloat16(h);
      if (out_f32) out_f32[(size_t)orow * f32_ld + f32_off + dir * 256 + tid] = h;
    }
    __syncthreads();
    pcur = pnext;
    st = dir ? (st - 1) : (st + 1);
  }
}

// ---------------------------------------------------------------------------
// argmax over obj_dists[:,1:151) -> preds (first max wins, like jnp.argmax)
// ---------------------------------------------------------------------------
__global__ void argmax_kernel(const float* __restrict__ dists, int* __restrict__ preds)
{
  const int row = blockIdx.x * 4 + (threadIdx.x >> 6);
  const int lane = threadIdx.x & 63;
  float best = -3.4e38f; int bi = 1000;
  for (int cc = 1 + lane; cc < 151; cc += 64) {
    float v = dists[(size_t)row * 663 + cc];
    if (v > best) { best = v; bi = cc; }
  }
  for (int off = 32; off > 0; off >>= 1) {
    float ov = __shfl_down(best, off);
    int   oi = __shfl_down(bi, off);
    if (ov > best || (ov == best && oi < bi)) { best = ov; bi = oi; }
  }
  if (lane == 0) preds[row] = bi;
}

// ---------------------------------------------------------------------------
// edge_in = [embed2[pred] (200) | enc (512, from FE) | fmaps (2048)] bf16
// ---------------------------------------------------------------------------
__global__ void edge_build(const int* __restrict__ preds,
                           const float* __restrict__ embed2,
                           const float* __restrict__ fmaps,
                           const __hip_bfloat16* __restrict__ FE,
                           __hip_bfloat16* __restrict__ EDGE)
{
  const int row = blockIdx.x, t = threadIdx.x;
  const int pr = preds[row];
  for (int c0 = t; c0 < 200; c0 += 256)
    EDGE[(size_t)row * EDGE_LD + c0] = __float2bfloat16(embed2[(size_t)pr * 200 + c0]);
  for (int c0 = t; c0 < 512; c0 += 256)
    EDGE[(size_t)row * EDGE_LD + 200 + c0] = FE[(size_t)row * FE_LD + c0];
  for (int c0 = t; c0 < 2048; c0 += 256)
    EDGE[(size_t)row * EDGE_LD + 712 + c0] = __float2bfloat16(fmaps[(size_t)row * 2048 + c0]);
}

// ---------------------------------------------------------------------------
extern "C" void kernel_launch(void* const* d_in, const int* in_sizes, int n_in,
                              void* d_out, int out_size, void* d_ws, size_t ws_size,
                              hipStream_t stream)
{
  const float* obj_fmaps    = (const float*)d_in[0];
  const float* obj_logits   = (const float*)d_in[1];
  const float* boxes        = (const float*)d_in[2];
  const float* obj_embed_w  = (const float*)d_in[4];
  const float* obj_embed2_w = (const float*)d_in[5];
  const float* bn_g = (const float*)d_in[6];
  const float* bn_b = (const float*)d_in[7];
  const float* bn_m = (const float*)d_in[8];
  const float* bn_v = (const float*)d_in[9];
  const float* pos_w = (const float*)d_in[10];
  const float* pos_b = (const float*)d_in[11];
  const float* obj_wih0 = (const float*)d_in[12];
  const float* obj_whh0 = (const float*)d_in[13];
  const float* obj_b0   = (const float*)d_in[14];
  const float* obj_wih1 = (const float*)d_in[15];
  const float* obj_whh1 = (const float*)d_in[16];
  const float* obj_b1   = (const float*)d_in[17];
  const float* edge_wih0 = (const float*)d_in[18];
  const float* edge_whh0 = (const float*)d_in[19];
  const float* edge_b0   = (const float*)d_in[20];
  const float* edge_wih1 = (const float*)d_in[21];
  const float* edge_whh1 = (const float*)d_in[22];
  const float* edge_b1   = (const float*)d_in[23];
  const float* dec_w = (const float*)d_in[24];
  const float* dec_b = (const float*)d_in[25];
  float* out = (float*)d_out;

  char* ws = (char*)d_ws;
  auto alloc = [&](size_t bytes) -> char* {
    char* p = ws; ws += (bytes + 255) & ~(size_t)255; return p;
  };
  __hip_bfloat16* FE     = (__hip_bfloat16*)alloc(4096ull * FE_LD * 2);
  __hip_bfloat16* EDGE   = (__hip_bfloat16*)alloc(4096ull * EDGE_LD * 2);
  float*          Pbuf   = (float*)alloc(4096ull * 2048 * 4);
  __hip_bfloat16* hseq   = (__hip_bfloat16*)alloc(4096ull * 512 * 2);
  __hip_bfloat16* probsb = (__hip_bfloat16*)alloc(4096ull * 192 * 2);
  __hip_bfloat16* wih0T  = (__hip_bfloat16*)alloc(2048ull * 2432 * 2);
  __hip_bfloat16* wih1T  = (__hip_bfloat16*)alloc(2048ull * 512 * 2);
  __hip_bfloat16* ewih0T = (__hip_bfloat16*)alloc(2048ull * 2816 * 2);
  __hip_bfloat16* ewih1T = (__hip_bfloat16*)alloc(2048ull * 512 * 2);
  __hip_bfloat16* embedT = (__hip_bfloat16*)alloc(256ull * 192 * 2);
  __hip_bfloat16* decT   = (__hip_bfloat16*)alloc(256ull * 2944 * 2);
  // packed whh set: wreg 65536 u32 | wlds 65536 u32 | wsc 2048 f32
  u32* whh0pk  = (u32*)alloc(133120ull * 4);
  u32* whh1pk  = (u32*)alloc(133120ull * 4);
  u32* ewhh0pk = (u32*)alloc(133120ull * 4);
  u32* ewhh1pk = (u32*)alloc(133120ull * 4);
  int*   perm  = (int*)alloc(4096 * 4);
  float* conf  = (float*)alloc(4096 * 4);
  int*   preds = (int*)alloc(4096 * 4);
  (void)in_sizes; (void)n_in; (void)out_size; (void)ws_size;

  auto tr = [&](const float* src, __hip_bfloat16* dst, int srcK, int srcN,
                int dstR, int dstC, int split, int soff) {
    dim3 g((dstC + 31) / 32, (dstR + 31) / 32);
    transpose_cast<<<g, dim3(256), 0, stream>>>(src, dst, srcK, srcN, dstR, dstC, split, soff);
  };
  for (int d = 0; d < 2; d++) {
    tr(obj_wih0 + (size_t)d * 2376 * 1024, wih0T + (size_t)d * 1024 * 2432, 2376, 1024, 1024, 2432, 0, 0);
    tr(obj_wih1 + (size_t)d * 512 * 1024,  wih1T + (size_t)d * 1024 * 512,  512, 1024, 1024, 512, 0, 0);
    tr(edge_wih0 + (size_t)d * 2760 * 1024, ewih0T + (size_t)d * 1024 * 2816, 2760, 1024, 1024, 2816, 0, 0);
    tr(edge_wih1 + (size_t)d * 512 * 1024,  ewih1T + (size_t)d * 1024 * 512,  512, 1024, 1024, 512, 0, 0);
  }
  tr(obj_embed_w, embedT, 151, 200, 256, 192, 0, 0);
  tr(dec_w, decT, 2888, 151, 256, 2944, 512, 2376);  // [enc|feats] ordering remap

  auto pk = [&](const float* whh, u32* dst) {
    pack_whh<<<dim3(8), dim3(256), 0, stream>>>(whh, dst, dst + 65536, (float*)(dst + 131072));
  };
  pk(obj_whh0, whh0pk); pk(obj_whh1, whh1pk); pk(edge_whh0, ewhh0pk); pk(edge_whh1, ewhh1pk);

  prep_kernel<<<dim3(4096), dim3(256), 0, stream>>>(
      obj_logits, obj_fmaps, boxes, bn_g, bn_b, bn_m, bn_v, pos_w, pos_b, FE, probsb, conf);
  sort_kernel<<<dim3(32), dim3(128), 0, stream>>>(conf, perm);

  auto gemm = [&](const void* A, int lda, const void* B, int ldb, int K, int N,
                  float* oF, __hip_bfloat16* oB, int ldc, const float* bias) {
    dim3 g(32, (N + 127) / 128);
    gemm_kernel<<<g, dim3(256), 0, stream>>>(
        (const u16*)A, lda, (const u16*)B, ldb, K, N, oF, oB, ldc, bias);
  };
  auto rec = [&](const float* P, const u32* wpk, int gat, int op,
                 __hip_bfloat16* ob, int old_, float* of, int fld, int foff) {
    rec_kernel<<<dim3(64), dim3(1024), 0, stream>>>(
        P, perm, wpk, wpk + 65536, (const float*)(wpk + 131072),
        gat, op, ob, old_, of, fld, foff);
  };

  // obj_embed -> FE cols [2560,2760)
  gemm(probsb, 192, embedT, 192, 192, 200, nullptr, FE + 2560, FE_LD, nullptr);
  // obj layer 0
  gemm((const u16*)FE + 512, FE_LD, wih0T, 2432, 2432, 2048, Pbuf, nullptr, 2048, obj_b0);
  rec(Pbuf, whh0pk, 1, 0, hseq, 512, nullptr, 0, 0);
  // obj layer 1 -> enc into FE cols [0,512)
  gemm(hseq, 512, wih1T, 512, 512, 2048, Pbuf, nullptr, 2048, obj_b1);
  rec(Pbuf, whh1pk, 0, 1, FE, FE_LD, nullptr, 0, 0);
  // decoder -> out cols [0,151)
  gemm(FE, FE_LD, decT, 2944, 2944, 151, out, nullptr, 663, dec_b);
  argmax_kernel<<<dim3(1024), dim3(256), 0, stream>>>(out, preds);
  edge_build<<<dim3(4096), dim3(256), 0, stream>>>(preds, obj_embed2_w, obj_fmaps, FE, EDGE);
  // edge layer 0
  gemm(EDGE, EDGE_LD, ewih0T, 2816, 2816, 2048, Pbuf, nullptr, 2048, edge_b0);
  rec(Pbuf, ewhh0pk, 1, 0, hseq, 512, nullptr, 0, 0);
  // edge layer 1 -> out cols [151,663)
  gemm(hseq, 512, ewih1T, 512, 512, 2048, Pbuf, nullptr, 2048, edge_b1);
  rec(Pbuf, ewhh1pk, 0, 1, nullptr, 0, out, 663, 151);
}